// Round 2
// 1235.700 us; speedup vs baseline: 1.0036x; 1.0036x over previous
//
#include <hip/hip_runtime.h>

// QuantizedEmbedding: gather int4-packed rows (stored as int32 in [-128,127]),
// unpack high/low nibble (trunc-div / positive-mod semantics), dequant with
// per-32-element group scales, write fp32.
//
// VOCAB=128000, DIM=4096, GROUPSIZE=32, PACKED=2048, NGROUPS=128
// indices: [4,4096] int32 ; weight: [VOCAB,2048] int32 ; scales: [VOCAB,128] f32
// out: [4,4096,4096] f32
//
// Roofline: ~410 MB total HBM traffic -> ~65 us at 6.3 TB/s.
//
// v2 structure: ONE WAVE PER TOKEN.
//  - token is wave-uniform -> row base lives in SGPRs (readfirstlane).
//  - lane l owns output float4 index (64*i + l), i = 0..15:
//      * weight load: int2 at packed-int2 index (64*i+l)  -> 512B fully
//        coalesced per instruction.
//      * output store: float4 at index (64*i+l) -> 1KB fully contiguous per
//        instruction (old kernel: 16B at 64B stride = quarter-coalesced).
//  - all 16 row loads issued before the unpack loop: 16 outstanding VMEM
//    ops per wave to hide ~900cy HBM latency on the random row gather.
//  - nontemporal stores: output is write-once, keep it out of L2/L3 so the
//    gathered weight rows stay cached for repeated indices.
//
// v2.1: __builtin_nontemporal_store needs a NATIVE vector type (clang
// ext_vector), not HIP's float4 class -> use f32x4.

#define PACKED  2048
#define NGROUPS 128
#define DIM     4096
#define WPB     4      // waves per block (256 threads)

typedef float f32x4 __attribute__((ext_vector_type(4)));

__global__ __launch_bounds__(256) void qembed_kernel(
    const int*   __restrict__ indices,
    const int*   __restrict__ weight,
    const float* __restrict__ scales,
    float*       __restrict__ out,
    int n_tokens)
{
    const int lane  = threadIdx.x & 63;
    const int wave  = threadIdx.x >> 6;
    const int token = blockIdx.x * WPB + wave;
    if (token >= n_tokens) return;

    // wave-uniform row index -> scalar regs, scalar address math
    const int row = __builtin_amdgcn_readfirstlane(indices[token]);

    const int2*  __restrict__ wrow = (const int2*)(weight + (long long)row * PACKED);
    const float* __restrict__ srow = scales + (long long)row * NGROUPS;
    float*       __restrict__ orow = out + (long long)token * DIM;

    // Issue the whole 8KB row as 16 coalesced dwordx2 loads (2KB in flight/wave).
    int2 w[16];
#pragma unroll
    for (int i = 0; i < 16; ++i)
        w[i] = wrow[64 * i + lane];

    // Output float4 j = 64*i + lane covers floats [4j, 4j+4): one group scale,
    // group index = j >> 3 = 8*i + (lane >> 3).
    const int cg = lane >> 3;

#pragma unroll
    for (int i = 0; i < 16; ++i) {
        const float s = srow[8 * i + cg];   // 32 distinct floats/instr, L1-hot
        const int a = w[i].x;
        const int b = w[i].y;
        // trunc-toward-zero div by 16 (high nibble), nonneg mod 16 (low nibble)
        const int e0 = (a + ((a >> 31) & 15)) >> 4;
        const int o0 = a & 15;
        const int e1 = (b + ((b >> 31) & 15)) >> 4;
        const int o1 = b & 15;
        f32x4 v;
        v.x = (float)(e0 - 8) * s;
        v.y = (float)(o0 - 8) * s;
        v.z = (float)(e1 - 8) * s;
        v.w = (float)(o1 - 8) * s;
        __builtin_nontemporal_store(v, (f32x4*)(orow + 4 * (64 * i + lane)));
    }
}

extern "C" void kernel_launch(void* const* d_in, const int* in_sizes, int n_in,
                              void* d_out, int out_size, void* d_ws, size_t ws_size,
                              hipStream_t stream) {
    const int*   indices = (const int*)d_in[0];
    const int*   weight  = (const int*)d_in[1];
    const float* scales  = (const float*)d_in[2];
    float*       out     = (float*)d_out;

    const int n_tokens = in_sizes[0];               // 16384
    const int blocks   = (n_tokens + WPB - 1) / WPB; // 4096
    qembed_kernel<<<blocks, 64 * WPB, 0, stream>>>(indices, weight, scales, out,
                                                   n_tokens);
}